// Round 10
// baseline (169.273 us; speedup 1.0000x reference)
//
#include <hip/hip_runtime.h>

// RelationalGraphConvLayer: out[b,m,u] = relu(sum_e (adj[b,e]@feat[b]) @ ker[b,e])
// B=256, E=5, N=128, ATOM=64, UNITS=128, fp32 in/out, bf16 MFMA compute.
//
// v9: contiguous adjacency streaming. v0-v8 invariantly delivered adj at
// ~1.2-1.5 TB/s; the one constant was the load-instruction shape (16 rows x
// 512 B stride x 16 B slivers = page-scattered). Here the whole block streams
// the 64 KB adj[e] slab LINEARLY (thread t: 16 consecutive floats at 16t; each
// 64-lane instruction = 1 KB contiguous), converts to bf16 in regs, and
// ds_write_b128's into the verified A-frag LDS layout -- the transpose moves
// from HBM to LDS. Double-buffered; slab e+1 issued at top of iter e.
// featB/kerF/YA layouts, matmul geometry, epilogue: v2-verbatim (verified).
// LDS: adjF 64K + kerF 32K + featB 16K + YA 32K = 144 KB. 1024 thr, grid 256.

typedef __attribute__((ext_vector_type(8))) short s8v;  // 8 x bf16 MFMA A/B frag
typedef __attribute__((ext_vector_type(4))) float f4v;  // MFMA C/D frag / float4

__device__ __forceinline__ short f2bf(float f) {
    // fp32 -> bf16 round-to-nearest-even (inputs finite; no NaN handling needed)
    unsigned u = __builtin_bit_cast(unsigned, f);
    u += 0x7FFFu + ((u >> 16) & 1u);
    return (short)(u >> 16);
}

// LDS-only barrier: drain this wave's LDS ops, then rendezvous. Global (vmcnt)
// loads stay outstanding across it. sched_barrier fences reordering.
__device__ __forceinline__ void lds_barrier() {
    asm volatile("s_waitcnt lgkmcnt(0)" ::: "memory");
    __builtin_amdgcn_s_barrier();
    __builtin_amdgcn_sched_barrier(0);
}

__global__ __launch_bounds__(1024, 4)
void rgc_kernel(const float* __restrict__ adj,
                const float* __restrict__ feat,
                const float* __restrict__ ker,
                float* __restrict__ out)
{
    // adjF[buf] tile (m16*4+k16), lane l, j: adj[16m16+(l&15)][32k16+8(l>>4)+j]  (A-frag)
    // kerF[buf] tile (u16*2+kk),  lane l, j: ker[32kk+8(l>>4)+j][16u16+(l&15)]   (B-frag)
    // featB     tile (d16*4+k16), lane l, j: feat[32k16+8(l>>4)+j][16d16+(l&15)] (B-frag)
    // YA[w]     tile kk,          lane l, j: Y[16g+(l&15)][32kk+8(l>>4)+j]       (A-frag)
    __shared__ __align__(16) short adjF[2][32 * 512];  // 64 KB
    __shared__ __align__(16) short kerF[2][16 * 512];  // 32 KB
    __shared__ __align__(16) short featB[16 * 512];    // 16 KB
    __shared__ __align__(16) short YA[16][1024];       // 32 KB

    const int tid  = threadIdx.x;
    const int w    = tid >> 6;    // wave 0..15
    const int lane = tid & 63;
    const int c16  = lane & 15;
    const int quad = lane >> 4;
    const int g    = w >> 1;      // row group: rows [16g, 16g+16)
    const int h    = w & 1;       // u-half: u16 tiles [4h, 4h+4)

    const int b = blockIdx.x;
    const float* adjB = adj  + (size_t)b * (5 * 128 * 128);
    const float* feG  = feat + (size_t)b * (128 * 64);
    const float* keG  = ker  + (size_t)b * (5 * 64 * 128);
    float*       outB = out  + (size_t)b * (128 * 128);

    // ---- adj staging map: thread t owns 16 CONSECUTIVE floats at slab+16t ----
    // row ar = t>>3 (one row per 8 threads), 16-col chunk ap = t&7.
    // Frag dest: tile (ar>>4, ap>>1); chunk covers quads {2*(ap&1), 2*(ap&1)+1}.
    const int ar   = tid >> 3;
    const int ap_  = tid & 7;
    const int aOff = ((ar >> 4) * 4 + (ap_ >> 1)) * 512 + (16 * (2 * (ap_ & 1)) + (ar & 15)) * 8;
    const float* aSrc = adjB + 16 * tid;   // contiguous: 64-lane instr = 1 KB linear

    // ---- prologue: issue adj slab 0 + feat + ker[0], all loads first ----
    f4v ax[4];
    #pragma unroll
    for (int i = 0; i < 4; ++i) ax[i] = *(const f4v*)(aSrc + 4 * i);

    const int fd  = tid & 63;        // feat: d (coalesced)
    const int fn0 = (tid >> 6) * 8;  // 8 consecutive n
    float fv[8];
    #pragma unroll
    for (int j = 0; j < 8; ++j) fv[j] = feG[(fn0 + j) * 64 + fd];

    const int ku  = tid & 127;       // ker: u (coalesced)
    const int kd0 = (tid >> 7) * 8;  // 8 consecutive d
    const int kOff = (ku >> 4) * 1024 + (kd0 >> 5) * 512 + ((kd0 >> 3) & 3) * 128 + (ku & 15) * 8;
    float kv[8];
    #pragma unroll
    for (int j = 0; j < 8; ++j) kv[j] = keG[(kd0 + j) * 128 + ku];

    // convert + store (compiler inserts counted waits per batch)
    {
        s8v lo, hi;
        #pragma unroll
        for (int j = 0; j < 4; ++j) {
            lo[j] = f2bf(ax[0][j]); lo[4 + j] = f2bf(ax[1][j]);
            hi[j] = f2bf(ax[2][j]); hi[4 + j] = f2bf(ax[3][j]);
        }
        *(s8v*)&adjF[0][aOff]       = lo;   // quads 2*(ap&1)
        *(s8v*)&adjF[0][aOff + 128] = hi;   // quads 2*(ap&1)+1
    }
    {
        s8v v;
        #pragma unroll
        for (int j = 0; j < 8; ++j) v[j] = f2bf(fv[j]);
        *(s8v*)&featB[((fd >> 4) * 4 + (fn0 >> 5)) * 512 + ((fn0 >> 3) & 3) * 128 + (fd & 15) * 8] = v;
    }
    {
        s8v v;
        #pragma unroll
        for (int j = 0; j < 8; ++j) v[j] = f2bf(kv[j]);
        *(s8v*)&kerF[0][kOff] = v;
    }
    lds_barrier();

    f4v oacc[4] = {};  // out tiles (m16 = g, u16 = 4h..4h+3)

    for (int e = 0; e < 5; ++e) {
        // ---- issue e+1 streams at the TOP (full-iteration latency shadow) ----
        f4v ax2[4];
        float kv2[8];
        if (e < 4) {
            const float* as = aSrc + (e + 1) * 16384;
            #pragma unroll
            for (int i = 0; i < 4; ++i) ax2[i] = *(const f4v*)(as + 4 * i);
            const float* kp = keG + (e + 1) * (64 * 128);
            #pragma unroll
            for (int j = 0; j < 8; ++j) kv2[j] = kp[(kd0 + j) * 128 + ku];
            __builtin_amdgcn_sched_barrier(0);  // loads may not sink below this point
        }

        // ---- matmul1: Y[16g..16g+16) = adj_e @ feat (A-frags from LDS) ----
        f4v yacc[4] = {};
        #pragma unroll
        for (int k16 = 0; k16 < 4; ++k16) {
            s8v af = *(const s8v*)&adjF[e & 1][(g * 4 + k16) * 512 + lane * 8];  // linear: conflict-free
            #pragma unroll
            for (int d16 = 0; d16 < 4; ++d16) {
                s8v bf = *(const s8v*)&featB[(d16 * 4 + k16) * 512 + lane * 8];
                yacc[d16] = __builtin_amdgcn_mfma_f32_16x16x32_bf16(af, bf, yacc[d16], 0, 0, 0);
            }
        }

        // ---- Y -> wave-private LDS in A-frag order (v2 remap, verified) ----
        #pragma unroll
        for (int d16 = 0; d16 < 4; ++d16) {
            const int base = (d16 >> 1) * 512 + ((2 * d16 + (c16 >> 3)) & 3) * 128 + (c16 & 7);
            #pragma unroll
            for (int r = 0; r < 4; ++r)
                YA[w][base + (4 * quad + r) * 8] = f2bf(yacc[d16][r]);
        }

        // ---- matmul2: out[rows g][u-half h] += Y @ ker_e ----
        {
            s8v afr0 = *(const s8v*)&YA[w][lane * 8];
            s8v afr1 = *(const s8v*)&YA[w][512 + lane * 8];
            #pragma unroll
            for (int n = 0; n < 4; ++n) {
                const int u16 = 4 * h + n;
                s8v b0 = *(const s8v*)&kerF[e & 1][(u16 * 2 + 0) * 512 + lane * 8];
                s8v b1 = *(const s8v*)&kerF[e & 1][(u16 * 2 + 1) * 512 + lane * 8];
                oacc[n] = __builtin_amdgcn_mfma_f32_16x16x32_bf16(afr0, b0, oacc[n], 0, 0, 0);
                oacc[n] = __builtin_amdgcn_mfma_f32_16x16x32_bf16(afr1, b1, oacc[n], 0, 0, 0);
            }
        }

        // ---- stage e+1 into the other buffers; barrier protects rotation ----
        if (e < 4) {
            s8v lo, hi;
            #pragma unroll
            for (int j = 0; j < 4; ++j) {
                lo[j] = f2bf(ax2[0][j]); lo[4 + j] = f2bf(ax2[1][j]);
                hi[j] = f2bf(ax2[2][j]); hi[4 + j] = f2bf(ax2[3][j]);
            }
            *(s8v*)&adjF[(e + 1) & 1][aOff]       = lo;
            *(s8v*)&adjF[(e + 1) & 1][aOff + 128] = hi;
            s8v v;
            #pragma unroll
            for (int j = 0; j < 8; ++j) v[j] = f2bf(kv2[j]);
            *(s8v*)&kerF[(e + 1) & 1][kOff] = v;
            lds_barrier();
        }
    }

    // ---- epilogue: relu + store ----
    #pragma unroll
    for (int n = 0; n < 4; ++n)
        #pragma unroll
        for (int r = 0; r < 4; ++r)
            outB[(16 * g + 4 * quad + r) * 128 + 16 * (4 * h + n) + c16] = fmaxf(oacc[n][r], 0.f);
}

extern "C" void kernel_launch(void* const* d_in, const int* in_sizes, int n_in,
                              void* d_out, int out_size, void* d_ws, size_t ws_size,
                              hipStream_t stream)
{
    const float* adj  = (const float*)d_in[0];
    const float* feat = (const float*)d_in[1];
    const float* ker  = (const float*)d_in[2];
    rgc_kernel<<<256, 1024, 0, stream>>>(adj, feat, ker, (float*)d_out);
}